// Round 5
// baseline (9076.661 us; speedup 1.0000x reference)
//
#include <hip/hip_runtime.h>
#include <stdint.h>

#define BATCH 8
#define HEADS 8
#define HM 128
#define WM 128
#define NPIX (HM*WM)      // 16384
#define DIMC 128
#define DH 64
#define GS 64
#define INNER 512
#define CS_LD 136         // fp32 row pad: 544 B/row, 16B-aligned
#define SW_LD 136         // u16 row pad: 272 B/row, 16B-aligned

typedef unsigned short u16;

__device__ __forceinline__ u16 f2bf(float f) {
    unsigned x = __float_as_uint(f);
    return (u16)((x + 0x7fffu + ((x >> 16) & 1u)) >> 16);   // RNE
}
__device__ __forceinline__ float bf2f(u16 u) { return __uint_as_float(((unsigned)u) << 16); }

struct alignas(8) US4 { u16 x, y, z, w; };
union BF8 { uint4 v; u16 s[8]; };

// ---------------------------------------------------------------------------
// wcatL[row = s*128+ci][co = h*64+g] = sum_c conv_x_w[row][h*64+c]*slice_w[g][c]
//                                      / clip(temp[h], 0.1, 5)
// ---------------------------------------------------------------------------
__global__ __launch_bounds__(256) void k_build_w(
    const float* __restrict__ wx, const float* __restrict__ slw,
    const float* __restrict__ temp, float* __restrict__ wcatL)
{
    __shared__ float sw_l[GS][DH + 1];
    __shared__ float wx_l[INNER];
    int row = blockIdx.x;            // 0..1151
    int t = threadIdx.x;
    for (int i = t; i < GS * DH; i += 256) sw_l[i >> 6][i & 63] = slw[i];
    for (int i = t; i < INNER; i += 256) wx_l[i] = wx[(size_t)row * INNER + i];
    __syncthreads();
#pragma unroll
    for (int j = 0; j < 2; j++) {
        int co = j * 256 + t;
        int h = co >> 6, g = co & 63;
        float s = 0.f;
        for (int c = 0; c < DH; c++) s = fmaf(wx_l[h * 64 + c], sw_l[g][c], s);
        float tv = fminf(fmaxf(temp[h], 0.1f), 5.0f);
        wcatL[(size_t)row * 512 + co] = s / tv;
    }
}

__global__ __launch_bounds__(512) void k_build_b(
    const float* __restrict__ bx, const float* __restrict__ slw,
    const float* __restrict__ slb, const float* __restrict__ temp,
    float* __restrict__ bcatL)
{
    int co = threadIdx.x;            // 0..511
    int h = co >> 6, g = co & 63;
    float s = slb[g];
    for (int c = 0; c < DH; c++) s = fmaf(bx[h * 64 + c], slw[g * 64 + c], s);
    float tv = fminf(fmaxf(temp[h], 0.1f), 5.0f);
    bcatL[co] = s / tv;
}

// ---------------------------------------------------------------------------
// Pass L: conv producing 512 logit channels; fused per-pixel softmax over
// each head's 64 logits (block = 128 px x 2 whole heads); sw stored bf16;
// slice_norm accumulated via one atomic per (h,g) per block.
// ---------------------------------------------------------------------------
union SmemL {
    struct { float As[32][128]; float Bs[32][128]; } c;   // 32 KiB conv tiles
    float Cs[64][CS_LD];                                  // 34 KiB epilogue
};

__global__ __launch_bounds__(256) void k_convL(
    const float* __restrict__ xin, const float* __restrict__ wcatL,
    const float* __restrict__ bcatL, u16* __restrict__ swb, float* __restrict__ norm)
{
    __shared__ SmemL sm;
    int pt = blockIdx.x;             // 0..1023 = b*128 + y
    int b = pt >> 7, y = pt & 127;
    int ct = blockIdx.y;             // heads 2ct, 2ct+1
    int cob = ct << 7;
    int t = threadIdx.x;
    int tm = t >> 4, tn = t & 15;
    int m_load = t & 127;
    int kk0 = (t >> 7) << 4;         // 0 or 16
    int kkB = t >> 3;                // 0..31
    int c16 = (t & 7) << 4;          // 0..112

    float acc[8][8];
#pragma unroll
    for (int i = 0; i < 8; i++)
#pragma unroll
        for (int j = 0; j < 8; j++) acc[i][j] = 0.f;

    for (int ky = 0; ky < 3; ky++) {
        int yy = y + ky - 1;
        bool yok = (unsigned)yy < (unsigned)HM;
        for (int kx = 0; kx < 3; kx++) {
            int col = m_load + kx - 1;
            bool ok = yok && ((unsigned)col < (unsigned)WM);
            const float* srcb = xin + (((size_t)b * NPIX + (size_t)yy * WM + col) * DIMC);
            int s = ky * 3 + kx;
            for (int ci0 = 0; ci0 < DIMC; ci0 += 32) {
                __syncthreads();
                float4 f0, f1, f2, f3;
                if (ok) {
                    const float4* p = (const float4*)(srcb + ci0 + kk0);
                    f0 = p[0]; f1 = p[1]; f2 = p[2]; f3 = p[3];
                } else {
                    f0 = f1 = f2 = f3 = make_float4(0.f, 0.f, 0.f, 0.f);
                }
                sm.c.As[kk0 + 0][m_load] = f0.x;  sm.c.As[kk0 + 1][m_load] = f0.y;
                sm.c.As[kk0 + 2][m_load] = f0.z;  sm.c.As[kk0 + 3][m_load] = f0.w;
                sm.c.As[kk0 + 4][m_load] = f1.x;  sm.c.As[kk0 + 5][m_load] = f1.y;
                sm.c.As[kk0 + 6][m_load] = f1.z;  sm.c.As[kk0 + 7][m_load] = f1.w;
                sm.c.As[kk0 + 8][m_load] = f2.x;  sm.c.As[kk0 + 9][m_load] = f2.y;
                sm.c.As[kk0 +10][m_load] = f2.z;  sm.c.As[kk0 +11][m_load] = f2.w;
                sm.c.As[kk0 +12][m_load] = f3.x;  sm.c.As[kk0 +13][m_load] = f3.y;
                sm.c.As[kk0 +14][m_load] = f3.z;  sm.c.As[kk0 +15][m_load] = f3.w;
                const float* wp = wcatL + ((size_t)(s * DIMC + ci0 + kkB)) * 512 + cob + c16;
                *(float4*)&sm.c.Bs[kkB][c16 + 0]  = *(const float4*)(wp + 0);
                *(float4*)&sm.c.Bs[kkB][c16 + 4]  = *(const float4*)(wp + 4);
                *(float4*)&sm.c.Bs[kkB][c16 + 8]  = *(const float4*)(wp + 8);
                *(float4*)&sm.c.Bs[kkB][c16 + 12] = *(const float4*)(wp + 12);
                __syncthreads();
#pragma unroll
                for (int kk = 0; kk < 32; kk++) {
                    float4 a0 = *(const float4*)&sm.c.As[kk][tm * 4];
                    float4 a1 = *(const float4*)&sm.c.As[kk][tm * 4 + 64];
                    float4 b0 = *(const float4*)&sm.c.Bs[kk][tn * 4];
                    float4 b1 = *(const float4*)&sm.c.Bs[kk][tn * 4 + 64];
                    float am[8] = {a0.x, a0.y, a0.z, a0.w, a1.x, a1.y, a1.z, a1.w};
                    float bn[8] = {b0.x, b0.y, b0.z, b0.w, b1.x, b1.y, b1.z, b1.w};
#pragma unroll
                    for (int i = 0; i < 8; i++)
#pragma unroll
                        for (int j = 0; j < 8; j++)
                            acc[i][j] = fmaf(am[i], bn[j], acc[i][j]);
                }
            }
        }
    }
    __syncthreads();   // conv done; Cs aliases As/Bs

    float4 bias0 = *(const float4*)&bcatL[cob + tn * 4];
    float4 bias1 = *(const float4*)&bcatL[cob + 64 + tn * 4];
    float bb[8] = {bias0.x, bias0.y, bias0.z, bias0.w, bias1.x, bias1.y, bias1.z, bias1.w};

    float normacc = 0.f;
    for (int s2 = 0; s2 < 2; s2++) {          // pixel halves 0..63 / 64..127
#pragma unroll
        for (int i = 0; i < 4; i++)
#pragma unroll
            for (int jj = 0; jj < 8; jj++)
                sm.Cs[tm * 4 + i][tn * 4 + (jj & 3) + ((jj >> 2) << 6)] = acc[s2 * 4 + i][jj] + bb[jj];
        __syncthreads();
        if (t < 128) {                        // one (pixel, head) per thread
            int p = t & 63, h = t >> 6;
            float mx = -1e30f;
            for (int j = 0; j < 64; j++) mx = fmaxf(mx, sm.Cs[p][h * 64 + j]);
            float ssum = 0.f;
            for (int j = 0; j < 64; j++) {
                float e = __expf(sm.Cs[p][h * 64 + j] - mx);
                sm.Cs[p][h * 64 + j] = e; ssum += e;
            }
            float inv = 1.f / ssum;
            for (int j = 0; j < 64; j++) sm.Cs[p][h * 64 + j] *= inv;
        }
        __syncthreads();
        if (t < 128) {                        // column-reduce for slice_norm
            float sacc = 0.f;
            for (int p = 0; p < 64; p++) sacc += sm.Cs[p][t];
            normacc += sacc;
        }
#pragma unroll
        for (int it = 0; it < 8; it++) {      // coalesced bf16 store of sw
            int q = it * 256 + t;             // 0..2047
            int hv = q >> 10, qq = q & 1023;
            int p = qq >> 4, gq = (qq & 15) * 4;
            US4 r;
            r.x = f2bf(sm.Cs[p][hv * 64 + gq + 0]);
            r.y = f2bf(sm.Cs[p][hv * 64 + gq + 1]);
            r.z = f2bf(sm.Cs[p][hv * 64 + gq + 2]);
            r.w = f2bf(sm.Cs[p][hv * 64 + gq + 3]);
            size_t idx = (((size_t)(b * HEADS + 2 * ct + hv) * NPIX) + (size_t)y * WM + s2 * 64 + p) * GS + gq;
            *(US4*)&swb[idx] = r;
        }
        __syncthreads();
    }
    if (t < 128) {
        int h = t >> 6, g = t & 63;
        atomicAdd(&norm[(b * HEADS + 2 * ct + h) * GS + g], normacc);
    }
}

// ---------------------------------------------------------------------------
// Pass F: conv producing 512 fx channels (conv_fx_w used directly, fp32);
// epilogue pools against sw (bf16) into slice_token partials.
// ---------------------------------------------------------------------------
union SmemF {
    struct { float As[32][128]; float Bs[32][128]; } c;            // 32 KiB
    struct { float Cs[64][CS_LD]; u16 Sw[64][SW_LD]; } e;          // 51 KiB
};

__global__ __launch_bounds__(256) void k_convF(
    const float* __restrict__ xin, const float* __restrict__ wfx,
    const float* __restrict__ bfx, const u16* __restrict__ swb,
    float* __restrict__ straw)
{
    __shared__ SmemF sm;
    int pt = blockIdx.x;             // 0..255 = b*32 + ygroup
    int b = pt >> 5, yg = pt & 31;
    int ct = blockIdx.y;             // heads 2ct, 2ct+1
    int cob = ct << 7;
    int t = threadIdx.x;
    int tm = t >> 4, tn = t & 15;
    int m_load = t & 127;
    int kk0 = (t >> 7) << 4;
    int kkB = t >> 3;
    int c16 = (t & 7) << 4;
    int tg = t & 15, tc = t >> 4;

    float4 bias0 = *(const float4*)&bfx[cob + tn * 4];
    float4 bias1 = *(const float4*)&bfx[cob + 64 + tn * 4];
    float bb[8] = {bias0.x, bias0.y, bias0.z, bias0.w, bias1.x, bias1.y, bias1.z, bias1.w};

    float pacc[2][4][4];
#pragma unroll
    for (int h = 0; h < 2; h++)
#pragma unroll
        for (int i = 0; i < 4; i++)
#pragma unroll
            for (int j = 0; j < 4; j++) pacc[h][i][j] = 0.f;

    for (int r = 0; r < 4; r++) {
        int y = yg * 4 + r;
        float acc[8][8];
#pragma unroll
        for (int i = 0; i < 8; i++)
#pragma unroll
            for (int j = 0; j < 8; j++) acc[i][j] = 0.f;

        for (int ky = 0; ky < 3; ky++) {
            int yy = y + ky - 1;
            bool yok = (unsigned)yy < (unsigned)HM;
            for (int kx = 0; kx < 3; kx++) {
                int col = m_load + kx - 1;
                bool ok = yok && ((unsigned)col < (unsigned)WM);
                const float* srcb = xin + (((size_t)b * NPIX + (size_t)yy * WM + col) * DIMC);
                int s = ky * 3 + kx;
                for (int ci0 = 0; ci0 < DIMC; ci0 += 32) {
                    __syncthreads();
                    float4 f0, f1, f2, f3;
                    if (ok) {
                        const float4* p = (const float4*)(srcb + ci0 + kk0);
                        f0 = p[0]; f1 = p[1]; f2 = p[2]; f3 = p[3];
                    } else {
                        f0 = f1 = f2 = f3 = make_float4(0.f, 0.f, 0.f, 0.f);
                    }
                    sm.c.As[kk0 + 0][m_load] = f0.x;  sm.c.As[kk0 + 1][m_load] = f0.y;
                    sm.c.As[kk0 + 2][m_load] = f0.z;  sm.c.As[kk0 + 3][m_load] = f0.w;
                    sm.c.As[kk0 + 4][m_load] = f1.x;  sm.c.As[kk0 + 5][m_load] = f1.y;
                    sm.c.As[kk0 + 6][m_load] = f1.z;  sm.c.As[kk0 + 7][m_load] = f1.w;
                    sm.c.As[kk0 + 8][m_load] = f2.x;  sm.c.As[kk0 + 9][m_load] = f2.y;
                    sm.c.As[kk0 +10][m_load] = f2.z;  sm.c.As[kk0 +11][m_load] = f2.w;
                    sm.c.As[kk0 +12][m_load] = f3.x;  sm.c.As[kk0 +13][m_load] = f3.y;
                    sm.c.As[kk0 +14][m_load] = f3.z;  sm.c.As[kk0 +15][m_load] = f3.w;
                    const float* wp = wfx + ((size_t)(s * DIMC + ci0 + kkB)) * 512 + cob + c16;
                    *(float4*)&sm.c.Bs[kkB][c16 + 0]  = *(const float4*)(wp + 0);
                    *(float4*)&sm.c.Bs[kkB][c16 + 4]  = *(const float4*)(wp + 4);
                    *(float4*)&sm.c.Bs[kkB][c16 + 8]  = *(const float4*)(wp + 8);
                    *(float4*)&sm.c.Bs[kkB][c16 + 12] = *(const float4*)(wp + 12);
                    __syncthreads();
#pragma unroll
                    for (int kk = 0; kk < 32; kk++) {
                        float4 a0 = *(const float4*)&sm.c.As[kk][tm * 4];
                        float4 a1 = *(const float4*)&sm.c.As[kk][tm * 4 + 64];
                        float4 b0 = *(const float4*)&sm.c.Bs[kk][tn * 4];
                        float4 b1 = *(const float4*)&sm.c.Bs[kk][tn * 4 + 64];
                        float am[8] = {a0.x, a0.y, a0.z, a0.w, a1.x, a1.y, a1.z, a1.w};
                        float bn[8] = {b0.x, b0.y, b0.z, b0.w, b1.x, b1.y, b1.z, b1.w};
#pragma unroll
                        for (int i = 0; i < 8; i++)
#pragma unroll
                            for (int j = 0; j < 8; j++)
                                acc[i][j] = fmaf(am[i], bn[j], acc[i][j]);
                    }
                }
            }
        }
        __syncthreads();   // conv done; e.Cs/e.Sw alias As/Bs

        for (int s2 = 0; s2 < 2; s2++) {
#pragma unroll
            for (int i = 0; i < 4; i++)
#pragma unroll
                for (int jj = 0; jj < 8; jj++)
                    sm.e.Cs[tm * 4 + i][tn * 4 + (jj & 3) + ((jj >> 2) << 6)] = acc[s2 * 4 + i][jj] + bb[jj];
#pragma unroll
            for (int it = 0; it < 4; it++) {
                int q = it * 256 + t;         // 0..1023
                int hv = q >> 9, qq = q & 511;
                int p = qq >> 3, gq = (qq & 7) * 8;
                size_t idx = (((size_t)(b * HEADS + 2 * ct + hv) * NPIX) + (size_t)yg * 512 + r * 128 + s2 * 64 + p) * GS + gq;
                uint4 v = *(const uint4*)&swb[idx];
                *(uint4*)&sm.e.Sw[p][hv * 64 + gq] = v;
            }
            __syncthreads();
            for (int p = 0; p < 64; p++) {
#pragma unroll
                for (int h = 0; h < 2; h++) {
                    US4 w4 = *(const US4*)&sm.e.Sw[p][h * 64 + tg * 4];
                    float4 cv = *(const float4*)&sm.e.Cs[p][h * 64 + tc * 4];
                    float wv[4] = {bf2f(w4.x), bf2f(w4.y), bf2f(w4.z), bf2f(w4.w)};
                    float cc[4] = {cv.x, cv.y, cv.z, cv.w};
#pragma unroll
                    for (int i = 0; i < 4; i++)
#pragma unroll
                        for (int j = 0; j < 4; j++)
                            pacc[h][i][j] = fmaf(wv[i], cc[j], pacc[h][i][j]);
                }
            }
            __syncthreads();
        }
    }
#pragma unroll
    for (int h = 0; h < 2; h++)
#pragma unroll
        for (int i = 0; i < 4; i++)
#pragma unroll
            for (int j = 0; j < 4; j++)
                atomicAdd(&straw[((size_t)(b * HEADS + 2 * ct + h) * 64 + tg * 4 + i) * 64 + tc * 4 + j],
                          pacc[h][i][j]);
}

// ---------------------------------------------------------------------------
// K4: per-(b,h): normalize slice_token, q/k/v, 64x64 attention, out_slice,
// fold out_w -> M1[bh][g][128]. One block per bh; 64 KiB LDS.
// ---------------------------------------------------------------------------
__global__ __launch_bounds__(256) void k_attn(
    const float* __restrict__ straw, const float* __restrict__ norm,
    const float* __restrict__ wq, const float* __restrict__ wk, const float* __restrict__ wv,
    const float* __restrict__ outw, float* __restrict__ m1)
{
    __shared__ float lds[4][64][64];
    int bh = blockIdx.x, h = bh & 7;
    int t = threadIdx.x;
    for (int i = t; i < 4096; i += 256) {
        int g = i >> 6;
        lds[0][g][i & 63] = straw[(size_t)bh * 4096 + i] / (norm[bh * 64 + g] + 1e-5f);
    }
    __syncthreads();
    int g = t >> 2, d0 = (t & 3) << 4;
    for (int d = d0; d < d0 + 16; d++) {
        float sq = 0.f, sk = 0.f, sv = 0.f;
        for (int c = 0; c < 64; c++) {
            float sc = lds[0][g][c];
            sq = fmaf(sc, wq[d * 64 + c], sq);
            sk = fmaf(sc, wk[d * 64 + c], sk);
            sv = fmaf(sc, wv[d * 64 + c], sv);
        }
        lds[1][g][d] = sq; lds[2][g][d] = sk; lds[3][g][d] = sv;
    }
    __syncthreads();
    float attnrow[16];
    for (int k2 = d0, i = 0; k2 < d0 + 16; k2++, i++) {
        float s = 0.f;
        for (int d = 0; d < 64; d++) s = fmaf(lds[1][g][d], lds[2][k2][d], s);
        attnrow[i] = s * 0.125f;
    }
    __syncthreads();
    for (int i = 0; i < 16; i++) lds[0][g][d0 + i] = attnrow[i];
    __syncthreads();
    if (t < 64) {
        float mx = -1e30f;
        for (int j = 0; j < 64; j++) mx = fmaxf(mx, lds[0][t][j]);
        float s = 0.f;
        for (int j = 0; j < 64; j++) { float e = __expf(lds[0][t][j] - mx); lds[0][t][j] = e; s += e; }
        float inv = 1.f / s;
        for (int j = 0; j < 64; j++) lds[0][t][j] *= inv;
    }
    __syncthreads();
    float osrow[16];
    for (int d = d0, i = 0; d < d0 + 16; d++, i++) {
        float s = 0.f;
        for (int kx = 0; kx < 64; kx++) s = fmaf(lds[0][g][kx], lds[3][kx][d], s);
        osrow[i] = s;
    }
    __syncthreads();
    for (int i = 0; i < 16; i++) lds[2][g][d0 + i] = osrow[i];
    __syncthreads();
    int dimb = (t & 3) << 5;
    for (int dim = dimb; dim < dimb + 32; dim++) {
        float s = 0.f;
        for (int c = 0; c < 64; c++)
            s = fmaf(lds[2][g][c], outw[(size_t)dim * INNER + h * 64 + c], s);
        m1[((size_t)bh * 64 + g) * DIMC + dim] = s;
    }
}

// ---------------------------------------------------------------------------
// K5: out[b][n][d] = sum_{h,g} sw[bh][n][g] * M1[bh][g][d] + out_b[d], fp32.
// ---------------------------------------------------------------------------
__global__ __launch_bounds__(256) void k_final(
    const u16* __restrict__ swb, const float* __restrict__ m1,
    const float* __restrict__ outb, float* __restrict__ out)
{
    __shared__ float As[32][68];    // sw^T: [g][n]
    __shared__ float Bs[32][128];   // M1:   [g][d]
    int b = blockIdx.x, nt = blockIdx.y;
    int t = threadIdx.x;
    int tn = t & 15, tm = t >> 4;
    float acc[4][8];
#pragma unroll
    for (int i = 0; i < 4; i++)
#pragma unroll
        for (int j = 0; j < 8; j++) acc[i][j] = 0.f;
    int n0 = nt * 64;
    int nl = t >> 2, gq = (t & 3) * 8;
    int gg = t >> 3, dd = (t & 7) * 16;
    for (int h = 0; h < HEADS; h++) {
        const u16* swp = swb + ((size_t)(b * HEADS + h) * NPIX + n0) * 64;
        const float* m1p = m1 + (size_t)(b * HEADS + h) * GS * DIMC;
        for (int g0 = 0; g0 < 64; g0 += 32) {
            __syncthreads();
            BF8 av8; av8.v = *(const uint4*)&swp[(size_t)nl * 64 + g0 + gq];
#pragma unroll
            for (int i = 0; i < 8; i++) As[gq + i][nl] = bf2f(av8.s[i]);
            const float* bp = m1p + (size_t)(g0 + gg) * DIMC + dd;
            *(float4*)&Bs[gg][dd + 0]  = *(const float4*)(bp + 0);
            *(float4*)&Bs[gg][dd + 4]  = *(const float4*)(bp + 4);
            *(float4*)&Bs[gg][dd + 8]  = *(const float4*)(bp + 8);
            *(float4*)&Bs[gg][dd + 12] = *(const float4*)(bp + 12);
            __syncthreads();
#pragma unroll
            for (int kk = 0; kk < 32; kk++) {
                float4 a = *(const float4*)&As[kk][tm * 4];
                float4 b0 = *(const float4*)&Bs[kk][tn * 4];
                float4 b1 = *(const float4*)&Bs[kk][tn * 4 + 64];
                float av[4] = {a.x, a.y, a.z, a.w};
                float bv[8] = {b0.x, b0.y, b0.z, b0.w, b1.x, b1.y, b1.z, b1.w};
#pragma unroll
                for (int i = 0; i < 4; i++)
#pragma unroll
                    for (int j = 0; j < 8; j++)
                        acc[i][j] = fmaf(av[i], bv[j], acc[i][j]);
            }
        }
    }
    float4 bias0 = *(const float4*)&outb[tn * 4];
    float4 bias1 = *(const float4*)&outb[64 + tn * 4];
#pragma unroll
    for (int i = 0; i < 4; i++) {
        size_t n = (size_t)n0 + tm * 4 + i;
        size_t rb = ((size_t)b * NPIX + n) * DIMC;
        float4 r0, r1;
        r0.x = acc[i][0] + bias0.x; r0.y = acc[i][1] + bias0.y;
        r0.z = acc[i][2] + bias0.z; r0.w = acc[i][3] + bias0.w;
        r1.x = acc[i][4] + bias1.x; r1.y = acc[i][5] + bias1.y;
        r1.z = acc[i][6] + bias1.z; r1.w = acc[i][7] + bias1.w;
        *(float4*)&out[rb + tn * 4] = r0;
        *(float4*)&out[rb + 64 + tn * 4] = r1;
    }
}

// ---------------------------------------------------------------------------
extern "C" void kernel_launch(void* const* d_in, const int* in_sizes, int n_in,
                              void* d_out, int out_size, void* d_ws, size_t ws_size,
                              hipStream_t stream)
{
    (void)in_sizes; (void)n_in; (void)out_size;
    const float* x    = (const float*)d_in[0];
    const float* wfx  = (const float*)d_in[1];
    const float* bfx  = (const float*)d_in[2];
    const float* wx   = (const float*)d_in[3];
    const float* bx   = (const float*)d_in[4];
    const float* slw  = (const float*)d_in[5];
    const float* slb  = (const float*)d_in[6];
    const float* temp = (const float*)d_in[7];
    const float* wq   = (const float*)d_in[8];
    const float* wk   = (const float*)d_in[9];
    const float* wv   = (const float*)d_in[10];
    const float* outw = (const float*)d_in[11];
    const float* outb = (const float*)d_in[12];
    float* out = (float*)d_out;
    float* W = (float*)d_ws;

    // workspace layout (float offsets)
    float* wcatL = W + 0;            //   589,824
    float* bcatL = W + 589824;       //       512
    float* norm  = W + 590336;       //     4,096   (zeroed)
    float* straw = W + 594432;       //   262,144   (zeroed, contiguous w/ norm)
    float* m1    = W + 856576;       //   524,288
    u16*   swb   = (u16*)(W + 1380864);  // 67,108,864 u16 = 128 MiB
    const size_t need = 1380864ull * 4 + 67108864ull * 2;   // 139,741,184 B
    if (ws_size < need) return;

    hipMemsetAsync(norm, 0, (4096 + 262144) * sizeof(float), stream);

    k_build_w<<<dim3(1152), 256, 0, stream>>>(wx, slw, temp, wcatL);
    k_build_b<<<dim3(1), 512, 0, stream>>>(bx, slw, slb, temp, bcatL);
    k_convL<<<dim3(1024, 4), 256, 0, stream>>>(x, wcatL, bcatL, swb, norm);
    k_convF<<<dim3(256, 4), 256, 0, stream>>>(x, wfx, bfx, swb, straw);
    k_attn<<<dim3(64), 256, 0, stream>>>(straw, norm, wq, wk, wv, outw, m1);
    k_final<<<dim3(8, 256), 256, 0, stream>>>(swb, m1, outb, out);
}